// Round 1
// 111.197 us; speedup vs baseline: 1.0260x; 1.0260x over previous
//
#include <hip/hip_runtime.h>

// SemiSparseCRFLoss on MI355X — R5: wave-covers-row shuffle halo.
// R4 baseline 114.1us; ~97us is harness reset (268MB ws poison + input
// restore), controllable part ~20us (crf_map latency-bound, pipes <10%).
// R5 change: SEG=8 x 64 lanes = full 512-px row per wave, so all halo
// pixels (cur right / nxt left / nxt right) live in neighbor lanes.
// Replace 12 scalar global edge-loads per segment with 3 shuffles per
// array (12 ds ops), and hoist all 16 float4 loads ahead of compute for
// max MLP. Arithmetic bitwise-identical to R4 (edge-lane shuffle garbage
// only consumed under left/right guards).

#define BATCH 16
#define HGT 512
#define WID 512
#define HW (HGT * WID)
#define SEG 8
#define SEGS_PER_ROW (WID / SEG)            // 64 = one wave per row
#define SEGS_PER_BATCH (HGT * SEGS_PER_ROW) // 32768 = 2^15
#define NSEG (BATCH * SEGS_PER_BATCH)       // 524288 = 2^19
#define NBLOCK 1024                          // each thread: 2 segments
#define BLOCKS_PER_BATCH 128                 // per batch-half

__device__ __forceinline__ float seg_loss(
        const float* __restrict__ yb,   // y_pr batch b, channel 1
        const float* __restrict__ ib,   // image batch b
        int seg) {
    const float inv2s2 = 22.2222222f;    // 1/(2*0.15^2)
    const float wxy1 = 0.60653066f;      // exp(-1/2): shifts (0,1),(1,0)
    const float wxy2 = 0.36787944f;      // exp(-1):   shifts (1,1),(1,-1)

    const int h = seg >> 6;
    const int lane = seg & 63;           // == lane id within the wave
    const int w0 = lane * SEG;
    const int hw = h * WID + w0;
    const bool hn = (h + 1 < HGT);       // wave-uniform
    const bool left = (lane > 0);
    const bool right = (lane < 63);

    // ---- Load phase: all 16 float4 issued before any dependent compute.
    // Arrays a=0..2: image channels; a=3: y_pr ch1.
    float c_[4][8];   // row h,   cols w0..w0+7
    float n_[4][8];   // row h+1, cols w0..w0+7
    #pragma unroll
    for (int a = 0; a < 4; a++) {
        const float* __restrict__ p = (a < 3) ? (ib + a * HW + hw) : (yb + hw);
        float4 a0 = *(const float4*)(p);
        float4 a1 = *(const float4*)(p + 4);
        c_[a][0] = a0.x; c_[a][1] = a0.y; c_[a][2] = a0.z; c_[a][3] = a0.w;
        c_[a][4] = a1.x; c_[a][5] = a1.y; c_[a][6] = a1.z; c_[a][7] = a1.w;
        if (hn) {
            float4 b0 = *(const float4*)(p + WID);
            float4 b1 = *(const float4*)(p + WID + 4);
            n_[a][0] = b0.x; n_[a][1] = b0.y; n_[a][2] = b0.z; n_[a][3] = b0.w;
            n_[a][4] = b1.x; n_[a][5] = b1.y; n_[a][6] = b1.z; n_[a][7] = b1.w;
        } else {
            #pragma unroll
            for (int k = 0; k < 8; k++) n_[a][k] = 0.f;
        }
    }

    // ---- Halo phase: neighbor-lane registers instead of global loads.
    // cR = (row h,   col w0+8), nR = (row h+1, col w0+8),
    // nL = (row h+1, col w0-1). Lane 0/63 get garbage — guarded below.
    float cR[4], nR[4], nL[4];
    #pragma unroll
    for (int a = 0; a < 4; a++) {
        cR[a] = __shfl_down(c_[a][0], 1);
        nR[a] = __shfl_down(n_[a][0], 1);
        nL[a] = __shfl_up(n_[a][7], 1);
    }

    // ---- d2 accumulation over 3 image channels.
    float d2r[8], d2d[8], d2dr[8], d2dl[8];
    #pragma unroll
    for (int j = 0; j < 8; j++) { d2r[j] = 0.f; d2d[j] = 0.f; d2dr[j] = 0.f; d2dl[j] = 0.f; }

    #pragma unroll
    for (int c = 0; c < 3; c++) {
        #pragma unroll
        for (int j = 0; j < 8; j++) {
            const float curj = c_[c][j];
            const float cr  = (j < 7) ? c_[c][j + 1] : cR[c];   // (h, w+1)
            const float nd  = n_[c][j];                          // (h+1, w)
            const float ndr = (j < 7) ? n_[c][j + 1] : nR[c];   // (h+1, w+1)
            const float ndl = (j > 0) ? n_[c][j - 1] : nL[c];   // (h+1, w-1)
            float dr  = curj - cr;   d2r[j]  += dr  * dr;
            float dd  = curj - nd;   d2d[j]  += dd  * dd;
            float ddr = curj - ndr;  d2dr[j] += ddr * ddr;
            float ddl = curj - ndl;  d2dl[j] += ddl * ddl;
        }
    }

    // ---- Loss accumulation (y = array 3).
    float s = 0.f;
    #pragma unroll
    for (int j = 0; j < 8; j++) {
        const float yj  = c_[3][j];
        const float yr  = (j < 7) ? c_[3][j + 1] : cR[3];
        const float yd  = n_[3][j];
        const float ydr = (j < 7) ? n_[3][j + 1] : nR[3];
        const float ydl = (j > 0) ? n_[3][j - 1] : nL[3];
        if (j < 7 || right) {                  // shift (0,1)
            float dy = yj - yr;
            float m = __expf(-d2r[j] * inv2s2) * wxy1 - 0.01f;
            s += m * dy * dy;
        }
        if (hn) {
            {                                   // shift (1,0)
                float dy = yj - yd;
                float m = __expf(-d2d[j] * inv2s2) * wxy1 - 0.01f;
                s += m * dy * dy;
            }
            if (j < 7 || right) {               // shift (1,1)
                float dy = yj - ydr;
                float m = __expf(-d2dr[j] * inv2s2) * wxy2 - 0.01f;
                s += m * dy * dy;
            }
            if (j > 0 || left) {                // shift (1,-1)
                float dy = yj - ydl;
                float m = __expf(-d2dl[j] * inv2s2) * wxy2 - 0.01f;
                s += m * dy * dy;
            }
        }
    }
    return s;
}

__global__ __launch_bounds__(256) void crf_map(
        const float* __restrict__ y_pr,
        const float* __restrict__ image,
        const int* __restrict__ image_class,
        double* __restrict__ partial) {
    // tid in [0, NSEG/2): batch-half 0 covers b=0..7, half 1 covers b=8..15.
    const int tid = blockIdx.x * 256 + threadIdx.x;
    const int seg = tid & (SEGS_PER_BATCH - 1);
    const int b0 = blockIdx.x >> 7;           // wave-uniform, in [0,8)
    const int b1 = b0 + 8;

    double local = 0.0;
    if (image_class[b0] != 0) {
        const float* yb = y_pr + (size_t)b0 * 2 * HW + HW;
        const float* ib = image + (size_t)b0 * 3 * HW;
        local += (double)seg_loss(yb, ib, seg);
    }
    if (image_class[b1] != 0) {
        const float* yb = y_pr + (size_t)b1 * 2 * HW + HW;
        const float* ib = image + (size_t)b1 * 3 * HW;
        local += (double)seg_loss(yb, ib, seg);
    }

    // wave64 reduction
    for (int off = 32; off > 0; off >>= 1)
        local += __shfl_down(local, off);

    __shared__ double sdata[4];
    const int lane = threadIdx.x & 63;
    const int wv = threadIdx.x >> 6;
    if (lane == 0) sdata[wv] = local;
    __syncthreads();
    if (threadIdx.x == 0)
        partial[blockIdx.x] = sdata[0] + sdata[1] + sdata[2] + sdata[3];
}

__global__ __launch_bounds__(256) void crf_reduce(
        const double* __restrict__ partial, float* __restrict__ out) {
    double s = 0.0;
    for (int i = threadIdx.x; i < NBLOCK; i += 256)
        s += partial[i];
    for (int off = 32; off > 0; off >>= 1)
        s += __shfl_down(s, off);
    __shared__ double sdata[4];
    const int lane = threadIdx.x & 63;
    const int wv = threadIdx.x >> 6;
    if (lane == 0) sdata[wv] = s;
    __syncthreads();
    if (threadIdx.x == 0) {
        double t = sdata[0] + sdata[1] + sdata[2] + sdata[3];
        out[0] = (float)(t * (1.0 / ((double)HW * BATCH * 4)));
    }
}

extern "C" void kernel_launch(void* const* d_in, const int* in_sizes, int n_in,
                              void* d_out, int out_size, void* d_ws, size_t ws_size,
                              hipStream_t stream) {
    const float* y_pr = (const float*)d_in[0];
    // d_in[1] (y_gt) unused by the reference
    const float* image = (const float*)d_in[2];
    const int* image_class = (const int*)d_in[3];
    float* out = (float*)d_out;
    double* partial = (double*)d_ws;   // NBLOCK doubles = 8 KB

    crf_map<<<NBLOCK, 256, 0, stream>>>(y_pr, image, image_class, partial);
    crf_reduce<<<1, 256, 0, stream>>>(partial, out);
}